// Round 1
// baseline (486.429 us; speedup 1.0000x reference)
//
#include <hip/hip_runtime.h>
#include <hip/hip_bf16.h>
#include <stdint.h>

// Problem constants
#define B_   128
#define N_   320
#define C_   768
#define H_   12
#define D_   64
#define NT_  (B_*N_)          // 40960 tokens
#define K3_  (3*C_)           // 2304

typedef __attribute__((ext_vector_type(8))) __bf16 bf16x8;
typedef __attribute__((ext_vector_type(4))) float  f32x4;

// fp32 -> bf16 round-to-nearest-even
__device__ __forceinline__ unsigned short f2bf(float f) {
  union { float f; unsigned u; } v; v.f = f;
  return (unsigned short)((v.u + 0x7fffu + ((v.u >> 16) & 1u)) >> 16);
}

// async global->LDS, 16B per lane; lds dst must be wave-uniform base
__device__ __forceinline__ void gload16(const unsigned short* g, unsigned short* l) {
  __builtin_amdgcn_global_load_lds((const __attribute__((address_space(1))) void*)g,
                                   (__attribute__((address_space(3))) void*)l,
                                   16, 0, 0);
}

// ---------------------------------------------------------------------------
// Kernel 1: concat(x1[:, :64], x2[:, 64:]) -> bf16, token-major [NT][C]
// ---------------------------------------------------------------------------
__global__ void prep_x(const float* __restrict__ x1, const float* __restrict__ x2,
                       unsigned short* __restrict__ xb) {
  const unsigned total4 = (unsigned)NT_ * C_ / 4;   // 7,864,320 float4s
  const unsigned stride = gridDim.x * blockDim.x;
  for (unsigned i = blockIdx.x * blockDim.x + threadIdx.x; i < total4; i += stride) {
    unsigned tok = i / (C_ / 4);
    unsigned n   = tok % N_;
    const float* src = (n < 64u) ? x1 : x2;     // same flat layout in both
    float4 v = *(const float4*)(src + (size_t)i * 4u);
    ushort4 o;
    o.x = f2bf(v.x); o.y = f2bf(v.y); o.z = f2bf(v.z); o.w = f2bf(v.w);
    *(ushort4*)(xb + (size_t)i * 4u) = o;
  }
}

// ---------------------------------------------------------------------------
// Kernel 2: weights -> bf16. q rows (first 768 rows of qkv_w) pre-scaled 1/8.
// ---------------------------------------------------------------------------
__global__ void prep_w(const float* __restrict__ qkv_w, const float* __restrict__ proj_w,
                       unsigned short* __restrict__ wq, unsigned short* __restrict__ wp) {
  const int QKV4 = (K3_ * C_) / 4;   // 442368
  const int Q4   = (C_ * C_) / 4;    // 147456 (q-weight region)
  const int P4   = (C_ * C_) / 4;
  int i = blockIdx.x * 256 + threadIdx.x;
  if (i < QKV4) {
    float s = (i < Q4) ? 0.125f : 1.0f;
    float4 v = *(const float4*)(qkv_w + (size_t)i * 4);
    ushort4 o;
    o.x = f2bf(v.x * s); o.y = f2bf(v.y * s); o.z = f2bf(v.z * s); o.w = f2bf(v.w * s);
    *(ushort4*)(wq + (size_t)i * 4) = o;
  } else if (i < QKV4 + P4) {
    int j = i - QKV4;
    float4 v = *(const float4*)(proj_w + (size_t)j * 4);
    ushort4 o;
    o.x = f2bf(v.x); o.y = f2bf(v.y); o.z = f2bf(v.z); o.w = f2bf(v.w);
    *(ushort4*)(wp + (size_t)j * 4) = o;
  }
}

// ---------------------------------------------------------------------------
// Kernel 3: QKV GEMM. C[m, nn] = sum_k xb[m,k] * wq[nn,k]
// 128x128 tile, BK=32, 4 waves, 16x16x32 bf16 MFMA (m97 structure).
// Epilogue scatters: q,k -> [bh][n][64] ; v -> [bh][64][n] (d-major, for attn)
// ---------------------------------------------------------------------------
__global__ void __launch_bounds__(256) gemm_qkv(const unsigned short* __restrict__ A,
                                                const unsigned short* __restrict__ W,
                                                unsigned short* __restrict__ qb,
                                                unsigned short* __restrict__ kb,
                                                unsigned short* __restrict__ vb) {
  __shared__ __align__(16) unsigned short As[128 * 32];
  __shared__ __align__(16) unsigned short Bs[128 * 32];
  const int tid  = threadIdx.x;
  const int lane = tid & 63;
  const int w    = tid >> 6;
  const int wr = w >> 1, wc = w & 1;
  const int lr = lane & 15, kg = lane >> 4;
  const int bid = blockIdx.x;
  const int bm = bid / 18, bn = bid % 18;
  const int row0 = bm * 128, col0 = bn * 128;

  // staging: chunk c = 1KB = 16 rows x 64B; wave w owns chunks {w, w+4}
  const int c0 = w, c1 = w + 4;
  const int sr = lane >> 2;     // row within chunk (0..15)
  const int sp = lane & 3;      // 16B part within 64B row
  const unsigned short* ga0 = A + (row0 + c0 * 16 + sr) * 768 + sp * 8;
  const unsigned short* ga1 = A + (row0 + c1 * 16 + sr) * 768 + sp * 8;
  const unsigned short* gb0 = W + (col0 + c0 * 16 + sr) * 768 + sp * 8;
  const unsigned short* gb1 = W + (col0 + c1 * 16 + sr) * 768 + sp * 8;
  unsigned short* la0 = &As[c0 * 512];
  unsigned short* la1 = &As[c1 * 512];
  unsigned short* lb0 = &Bs[c0 * 512];
  unsigned short* lb1 = &Bs[c1 * 512];

  f32x4 acc[4][4] = {};

  for (int kk = 0; kk < 768; kk += 32) {
    gload16(ga0 + kk, la0);
    gload16(ga1 + kk, la1);
    gload16(gb0 + kk, lb0);
    gload16(gb1 + kk, lb1);
    __syncthreads();
    bf16x8 af[4], bfr[4];
#pragma unroll
    for (int i = 0; i < 4; i++)
      af[i] = *(const bf16x8*)&As[(wr * 64 + i * 16 + lr) * 32 + kg * 8];
#pragma unroll
    for (int j = 0; j < 4; j++)
      bfr[j] = *(const bf16x8*)&Bs[(wc * 64 + j * 16 + lr) * 32 + kg * 8];
#pragma unroll
    for (int i = 0; i < 4; i++)
#pragma unroll
      for (int j = 0; j < 4; j++)
        acc[i][j] = __builtin_amdgcn_mfma_f32_16x16x32_bf16(af[i], bfr[j], acc[i][j], 0, 0, 0);
    __syncthreads();
  }

  // epilogue: C/D layout col=lane&15, row=(lane>>4)*4+reg (m89/m91 verified)
  const int which = col0 / 768;            // 0=q 1=k 2=v (128 | 768, uniform)
  const int colb  = col0 - which * 768 + wc * 64;
  if (which == 2) {
#pragma unroll
    for (int i = 0; i < 4; i++) {
      const int m0 = row0 + wr * 64 + i * 16 + kg * 4;  // 4-aligned, no b straddle
      const unsigned bq = (unsigned)m0 / 320u;
      const unsigned t0 = (unsigned)m0 - bq * 320u;
#pragma unroll
      for (int j = 0; j < 4; j++) {
        const int nn = colb + j * 16 + lr;
        const int h = nn >> 6, dd = nn & 63;
        ushort4 o;
        o.x = f2bf(acc[i][j][0]); o.y = f2bf(acc[i][j][1]);
        o.z = f2bf(acc[i][j][2]); o.w = f2bf(acc[i][j][3]);
        *(ushort4*)&vb[(((int)bq * 12 + h) * 64 + dd) * 320 + (int)t0] = o;
      }
    }
  } else {
    unsigned short* dst = (which == 0) ? qb : kb;
#pragma unroll
    for (int i = 0; i < 4; i++) {
      const int m0 = row0 + wr * 64 + i * 16 + kg * 4;
      const unsigned bq = (unsigned)m0 / 320u;
      const unsigned t0 = (unsigned)m0 - bq * 320u;
#pragma unroll
      for (int j = 0; j < 4; j++) {
        const int nn = colb + j * 16 + lr;
        const int h = nn >> 6, dd = nn & 63;
        const int base = (((int)bq * 12 + h) * 320 + (int)t0) * 64 + dd;
#pragma unroll
        for (int r = 0; r < 4; r++)
          dst[base + r * 64] = f2bf(acc[i][j][r]);
      }
    }
  }
}

// ---------------------------------------------------------------------------
// Kernel 4: flash attention. Block = (bh, qtile of 64 queries), 4 waves x 16 q.
// qtile 0 -> keys [0,64); qtiles 1..4 -> keys [0,320). KV chunks of 64 keys
// staged in LDS with XOR swizzle (byte ^= (row&7)<<4) via pre-swizzled
// global_load_lds source (rule #21). q pre-scaled by 1/8 in weights.
// ---------------------------------------------------------------------------
__global__ void __launch_bounds__(256) attn(const unsigned short* __restrict__ qb,
                                            const unsigned short* __restrict__ kb,
                                            const unsigned short* __restrict__ vb,
                                            unsigned short* __restrict__ ab) {
  __shared__ __align__(16) unsigned short Ks[64 * 64];   // [key][d] swizzled
  __shared__ __align__(16) unsigned short Vt[64 * 64];   // [d][key] swizzled
  __shared__ __align__(16) unsigned short Pl[4 * 16 * 64]; // per-wave P [q][key] swizzled
  const int bid = blockIdx.x;
  const int qt = bid % 5, bh = bid / 5;
  const int tid = threadIdx.x, lane = tid & 63, w = tid >> 6;
  const int lr = lane & 15, kg = lane >> 4;

  // Q fragments in registers: A row = lane&15, k(d) = kg*8..+7 per half
  const int qrow = qt * 64 + w * 16 + lr;
  const unsigned short* qptr = qb + (bh * 320 + qrow) * 64;
  const bf16x8 qa0 = *(const bf16x8*)(qptr + kg * 8);
  const bf16x8 qa1 = *(const bf16x8*)(qptr + 32 + kg * 8);

  f32x4 o[4] = {};
  float mrun[4] = {-1e30f, -1e30f, -1e30f, -1e30f};
  float lrun[4] = {0.f, 0.f, 0.f, 0.f};
  const int nchunk = (qt == 0) ? 1 : 5;

  // staging: chunk = 1KB = 8 rows x 128B; wave w owns chunks {w, w+4}
  const int c0 = w, c1 = w + 4;
  const int srow0 = c0 * 8 + (lane >> 3);
  const int srow1 = c1 * 8 + (lane >> 3);
  const int slot  = lane & 7;
  const int part0 = slot ^ (srow0 & 7);   // inverse-swizzled source part
  const int part1 = slot ^ (srow1 & 7);
  const unsigned short* kbase = kb + bh * 320 * 64;
  const unsigned short* vbase = vb + bh * 64 * 320;
  unsigned short* lk0 = &Ks[c0 * 512];
  unsigned short* lk1 = &Ks[c1 * 512];
  unsigned short* lv0 = &Vt[c0 * 512];
  unsigned short* lv1 = &Vt[c1 * 512];
  char* PwB = (char*)&Pl[w * 1024];       // this wave's 2KB P region

  for (int kc = 0; kc < nchunk; kc++) {
    gload16(kbase + (kc * 64 + srow0) * 64 + part0 * 8, lk0);
    gload16(kbase + (kc * 64 + srow1) * 64 + part1 * 8, lk1);
    gload16(vbase + srow0 * 320 + kc * 64 + part0 * 8, lv0);
    gload16(vbase + srow1 * 320 + kc * 64 + part1 * 8, lv1);
    __syncthreads();

    // S = Q @ K^T (logits; scale folded into q)
    f32x4 s[4];
#pragma unroll
    for (int kt = 0; kt < 4; kt++) {
      const int key = kt * 16 + lr;
      const char* kr = (const char*)Ks + key * 128;
      const unsigned sw = (unsigned)((key & 7) << 4);
      bf16x8 k0 = *(const bf16x8*)(kr + ((kg * 16) ^ sw));
      bf16x8 k1 = *(const bf16x8*)(kr + ((64 + kg * 16) ^ sw));
      f32x4 z = {0.f, 0.f, 0.f, 0.f};
      z = __builtin_amdgcn_mfma_f32_16x16x32_bf16(qa0, k0, z, 0, 0, 0);
      z = __builtin_amdgcn_mfma_f32_16x16x32_bf16(qa1, k1, z, 0, 0, 0);
      s[kt] = z;
    }

    // online softmax; row q = kg*4+r, cols = key = kt*16 + (lane&15)
#pragma unroll
    for (int r = 0; r < 4; r++) {
      float rm = fmaxf(fmaxf(s[0][r], s[1][r]), fmaxf(s[2][r], s[3][r]));
      rm = fmaxf(rm, __shfl_xor(rm, 1));
      rm = fmaxf(rm, __shfl_xor(rm, 2));
      rm = fmaxf(rm, __shfl_xor(rm, 4));
      rm = fmaxf(rm, __shfl_xor(rm, 8));
      const float mn = fmaxf(mrun[r], rm);
      const float alpha = __expf(mrun[r] - mn);
      mrun[r] = mn;
      const int q = kg * 4 + r;
      char* prow = PwB + q * 128;
      const unsigned sw = (unsigned)((q & 7) << 4);
      float rs = 0.f;
#pragma unroll
      for (int kt = 0; kt < 4; kt++) {
        const float p = __expf(s[kt][r] - mn);
        rs += p;
        const int key = kt * 16 + lr;
        *(unsigned short*)(prow + ((key * 2) ^ sw)) = f2bf(p);
      }
      rs += __shfl_xor(rs, 1);
      rs += __shfl_xor(rs, 2);
      rs += __shfl_xor(rs, 4);
      rs += __shfl_xor(rs, 8);
      lrun[r] = lrun[r] * alpha + rs;
#pragma unroll
      for (int dt = 0; dt < 4; dt++) o[dt][r] *= alpha;
    }

    // wave-local P write -> read fence
    asm volatile("s_waitcnt lgkmcnt(0)" ::: "memory");

    // O += P @ V
    {
      const char* par = (const char*)PwB + lr * 128;
      const unsigned swp = (unsigned)((lr & 7) << 4);
      bf16x8 p0 = *(const bf16x8*)(par + ((kg * 16) ^ swp));
      bf16x8 p1 = *(const bf16x8*)(par + ((64 + kg * 16) ^ swp));
#pragma unroll
      for (int dt = 0; dt < 4; dt++) {
        const int d = dt * 16 + lr;
        const char* vr = (const char*)Vt + d * 128;
        const unsigned swv = (unsigned)((d & 7) << 4);
        bf16x8 v0 = *(const bf16x8*)(vr + ((kg * 16) ^ swv));
        bf16x8 v1 = *(const bf16x8*)(vr + ((64 + kg * 16) ^ swv));
        o[dt] = __builtin_amdgcn_mfma_f32_16x16x32_bf16(p0, v0, o[dt], 0, 0, 0);
        o[dt] = __builtin_amdgcn_mfma_f32_16x16x32_bf16(p1, v1, o[dt], 0, 0, 0);
      }
    }
    __syncthreads();
  }

  // epilogue: normalize, write bf16 to ab[token][h*64 + d]
  const int b = bh / 12, h = bh - b * 12;
#pragma unroll
  for (int r = 0; r < 4; r++) {
    const float inv = 1.0f / lrun[r];
    const int token = b * 320 + qt * 64 + w * 16 + kg * 4 + r;
    unsigned short* orow = ab + token * 768 + h * 64;
#pragma unroll
    for (int dt = 0; dt < 4; dt++)
      orow[dt * 16 + lr] = f2bf(o[dt][r] * inv);
  }
}

// ---------------------------------------------------------------------------
// Kernel 5: proj GEMM + bias. out[m, nn] = sum_k ab[m,k]*wp[nn,k] + b[nn], fp32
// ---------------------------------------------------------------------------
__global__ void __launch_bounds__(256) gemm_proj(const unsigned short* __restrict__ A,
                                                 const unsigned short* __restrict__ W,
                                                 const float* __restrict__ bias,
                                                 float* __restrict__ out) {
  __shared__ __align__(16) unsigned short As[128 * 32];
  __shared__ __align__(16) unsigned short Bs[128 * 32];
  const int tid  = threadIdx.x;
  const int lane = tid & 63;
  const int w    = tid >> 6;
  const int wr = w >> 1, wc = w & 1;
  const int lr = lane & 15, kg = lane >> 4;
  const int bid = blockIdx.x;
  const int bm = bid / 6, bn = bid % 6;
  const int row0 = bm * 128, col0 = bn * 128;

  const int c0 = w, c1 = w + 4;
  const int sr = lane >> 2;
  const int sp = lane & 3;
  const unsigned short* ga0 = A + (row0 + c0 * 16 + sr) * 768 + sp * 8;
  const unsigned short* ga1 = A + (row0 + c1 * 16 + sr) * 768 + sp * 8;
  const unsigned short* gb0 = W + (col0 + c0 * 16 + sr) * 768 + sp * 8;
  const unsigned short* gb1 = W + (col0 + c1 * 16 + sr) * 768 + sp * 8;
  unsigned short* la0 = &As[c0 * 512];
  unsigned short* la1 = &As[c1 * 512];
  unsigned short* lb0 = &Bs[c0 * 512];
  unsigned short* lb1 = &Bs[c1 * 512];

  f32x4 acc[4][4] = {};

  for (int kk = 0; kk < 768; kk += 32) {
    gload16(ga0 + kk, la0);
    gload16(ga1 + kk, la1);
    gload16(gb0 + kk, lb0);
    gload16(gb1 + kk, lb1);
    __syncthreads();
    bf16x8 af[4], bfr[4];
#pragma unroll
    for (int i = 0; i < 4; i++)
      af[i] = *(const bf16x8*)&As[(wr * 64 + i * 16 + lr) * 32 + kg * 8];
#pragma unroll
    for (int j = 0; j < 4; j++)
      bfr[j] = *(const bf16x8*)&Bs[(wc * 64 + j * 16 + lr) * 32 + kg * 8];
#pragma unroll
    for (int i = 0; i < 4; i++)
#pragma unroll
      for (int j = 0; j < 4; j++)
        acc[i][j] = __builtin_amdgcn_mfma_f32_16x16x32_bf16(af[i], bfr[j], acc[i][j], 0, 0, 0);
    __syncthreads();
  }

#pragma unroll
  for (int j = 0; j < 4; j++) {
    const int nn = col0 + wc * 64 + j * 16 + lr;
    const float bv = bias[nn];
#pragma unroll
    for (int i = 0; i < 4; i++) {
      const int m0 = row0 + wr * 64 + i * 16 + kg * 4;
      float* po = out + m0 * 768 + nn;
#pragma unroll
      for (int r = 0; r < 4; r++)
        po[r * 768] = acc[i][j][r] + bv;
    }
  }
}

// ---------------------------------------------------------------------------
extern "C" void kernel_launch(void* const* d_in, const int* in_sizes, int n_in,
                              void* d_out, int out_size, void* d_ws, size_t ws_size,
                              hipStream_t stream) {
  (void)in_sizes; (void)n_in; (void)out_size; (void)ws_size;
  const float* x1     = (const float*)d_in[0];
  const float* x2     = (const float*)d_in[1];
  const float* qkv_w  = (const float*)d_in[2];
  const float* proj_w = (const float*)d_in[3];
  const float* proj_b = (const float*)d_in[4];
  float* out = (float*)d_out;

  // workspace layout (ushort elems); total = 319,291,392 bytes
  const size_t TOK = (size_t)NT_ * C_;          // 31,457,280
  unsigned short* xb = (unsigned short*)d_ws;
  unsigned short* qb = xb + TOK;
  unsigned short* kb = qb + TOK;
  unsigned short* vb = kb + TOK;
  unsigned short* ab = vb + TOK;
  unsigned short* wq = ab + TOK;
  unsigned short* wp = wq + (size_t)K3_ * C_;   // 1,769,472

  prep_x<<<8192, 256, 0, stream>>>(x1, x2, xb);
  prep_w<<<2304, 256, 0, stream>>>(qkv_w, proj_w, wq, wp);
  gemm_qkv<<<320 * 18, 256, 0, stream>>>(xb, wq, qb, kb, vb);
  attn<<<1536 * 5, 256, 0, stream>>>(qb, kb, vb, ab);
  gemm_proj<<<320 * 6, 256, 0, stream>>>(ab, wp, proj_b, out);
}

// Round 2
// 409.927 us; speedup vs baseline: 1.1866x; 1.1866x over previous
//
#include <hip/hip_runtime.h>
#include <hip/hip_bf16.h>
#include <stdint.h>

// Problem constants
#define B_   128
#define N_   320
#define C_   768
#define H_   12
#define D_   64
#define NT_  (B_*N_)          // 40960 tokens
#define K3_  (3*C_)           // 2304
#define NKT  12               // K tiles of 64 (K=768)
#define TE   (256*64)         // elems per 256x64 LDS tile

typedef __attribute__((ext_vector_type(8))) __bf16 bf16x8;
typedef __attribute__((ext_vector_type(4))) float  f32x4;

// fp32 -> bf16 round-to-nearest-even
__device__ __forceinline__ unsigned short f2bf(float f) {
  union { float f; unsigned u; } v; v.f = f;
  return (unsigned short)((v.u + 0x7fffu + ((v.u >> 16) & 1u)) >> 16);
}

// async global->LDS, 16B per lane; lds dst wave-uniform base (+lane*16 by HW)
__device__ __forceinline__ void gload16(const unsigned short* g, unsigned short* l) {
  __builtin_amdgcn_global_load_lds((const __attribute__((address_space(1))) void*)g,
                                   (__attribute__((address_space(3))) void*)l,
                                   16, 0, 0);
}

// ---------------------------------------------------------------------------
// Kernel 1: concat(x1[:, :64], x2[:, 64:]) -> bf16, token-major [NT][C]
// ---------------------------------------------------------------------------
__global__ void prep_x(const float* __restrict__ x1, const float* __restrict__ x2,
                       unsigned short* __restrict__ xb) {
  const unsigned total4 = (unsigned)NT_ * C_ / 4;
  const unsigned stride = gridDim.x * blockDim.x;
  for (unsigned i = blockIdx.x * blockDim.x + threadIdx.x; i < total4; i += stride) {
    unsigned tok = i / (C_ / 4);
    unsigned n   = tok % N_;
    const float* src = (n < 64u) ? x1 : x2;
    float4 v = *(const float4*)(src + (size_t)i * 4u);
    ushort4 o;
    o.x = f2bf(v.x); o.y = f2bf(v.y); o.z = f2bf(v.z); o.w = f2bf(v.w);
    *(ushort4*)(xb + (size_t)i * 4u) = o;
  }
}

// ---------------------------------------------------------------------------
// Kernel 2: weights -> bf16. q rows (first 768 rows of qkv_w) pre-scaled 1/8.
// ---------------------------------------------------------------------------
__global__ void prep_w(const float* __restrict__ qkv_w, const float* __restrict__ proj_w,
                       unsigned short* __restrict__ wq, unsigned short* __restrict__ wp) {
  const int QKV4 = (K3_ * C_) / 4;
  const int Q4   = (C_ * C_) / 4;
  const int P4   = (C_ * C_) / 4;
  int i = blockIdx.x * 256 + threadIdx.x;
  if (i < QKV4) {
    float s = (i < Q4) ? 0.125f : 1.0f;
    float4 v = *(const float4*)(qkv_w + (size_t)i * 4);
    ushort4 o;
    o.x = f2bf(v.x * s); o.y = f2bf(v.y * s); o.z = f2bf(v.z * s); o.w = f2bf(v.w * s);
    *(ushort4*)(wq + (size_t)i * 4) = o;
  } else if (i < QKV4 + P4) {
    int j = i - QKV4;
    float4 v = *(const float4*)(proj_w + (size_t)j * 4);
    ushort4 o;
    o.x = f2bf(v.x); o.y = f2bf(v.y); o.z = f2bf(v.z); o.w = f2bf(v.w);
    *(ushort4*)(wp + (size_t)j * 4) = o;
  }
}

// ---------------------------------------------------------------------------
// 256x256x(BK=64) 8-wave deep-pipelined K-loop (m201 template, plain HIP).
// LDS tiles [256 rows][64 k], row-major, XOR-swizzled: 16B part p of row r
// holds global part p^(r&7) (stage source pre-swizzled; reads apply same XOR).
// A staged 1 K-tile ahead (A-region dead across tile boundary); B staged 2
// K-tiles ahead (B-region dead after phase 0 of its tile, since B-frags are
// register-resident for phases 1-3). Boundary wait = counted vmcnt(4).
// ---------------------------------------------------------------------------
__device__ __forceinline__ void stage_half(const unsigned short* __restrict__ g,
                                           int grow0, int kt,
                                           unsigned short* lds_tile, int half,
                                           int w, int lane) {
  const int r0 = half * 128 + w * 16;      // wave's 16 rows in this half
  const int rr = lane >> 3;                // 0..7
  const int sp = (lane & 7) ^ rr;          // pre-swizzled source part
#pragma unroll
  for (int i = 0; i < 2; i++) {
    const unsigned short* gp = g + (size_t)(grow0 + r0 + i * 8 + rr) * 768 + kt * 64 + sp * 8;
    unsigned short* lp = lds_tile + (r0 + i * 8) * 64;
    gload16(gp, lp);
  }
}

__device__ __forceinline__ bf16x8 lds_frag(const unsigned short* tile, int row, int pp) {
  const char* p = (const char*)tile + row * 128 + (((pp) ^ (row & 7)) * 16);
  return *(const bf16x8*)p;
}

__device__ __forceinline__ void gemm_kloop(const unsigned short* __restrict__ Ag,
                                           const unsigned short* __restrict__ Wg,
                                           int row0, int col0,
                                           unsigned short* As, unsigned short* Bs,
                                           f32x4 (&acc)[8][4]) {
  const int tid = threadIdx.x, lane = tid & 63, w = tid >> 6;
  const int wr = w >> 2, wc = w & 3;       // 2M x 4N wave grid
  const int lr = lane & 15, kg = lane >> 4;

  // prologue: tile0 (A,B) + tile1 (B only; A(1) staged during tile 0)
  stage_half(Ag, row0, 0, As, 0, w, lane);
  stage_half(Ag, row0, 0, As, 1, w, lane);
  stage_half(Wg, col0, 0, Bs, 0, w, lane);
  stage_half(Wg, col0, 0, Bs, 1, w, lane);
  stage_half(Wg, col0, 1, Bs + TE, 0, w, lane);
  stage_half(Wg, col0, 1, Bs + TE, 1, w, lane);
  asm volatile("s_waitcnt vmcnt(4)" ::: "memory");   // tile0 landed; B(1) in flight
  __builtin_amdgcn_s_barrier();
  asm volatile("" ::: "memory");

  bf16x8 bf_[2][4];                        // B-frags [ks][nf], live across phases
#pragma unroll 2
  for (int t = 0; t < NKT; ++t) {
    unsigned short* Ac = As + (t & 1) * TE;
    unsigned short* Bc = Bs + (t & 1) * TE;
#pragma unroll
    for (int q = 0; q < 4; ++q) {
      // --- ds-load register subtile ---
      bf16x8 af_[2][2];                    // A-frags [f][ks]
#pragma unroll
      for (int f = 0; f < 2; ++f)
#pragma unroll
        for (int ks = 0; ks < 2; ++ks)
          af_[f][ks] = lds_frag(Ac, wr * 128 + q * 32 + f * 16 + lr, ks * 4 + kg);
      if (q == 0) {
#pragma unroll
        for (int nf = 0; nf < 4; ++nf)
#pragma unroll
          for (int ks = 0; ks < 2; ++ks)
            bf_[ks][nf] = lds_frag(Bc, wc * 64 + nf * 16 + lr, ks * 4 + kg);
      }
      // --- stage 1 half-tile prefetch ---
      if (q == 0)      { if (t + 1 < NKT) stage_half(Ag, row0, t + 1, As + ((t + 1) & 1) * TE, 0, w, lane); }
      else if (q == 1) { if (t + 1 < NKT) stage_half(Ag, row0, t + 1, As + ((t + 1) & 1) * TE, 1, w, lane); }
      else if (q == 2) { if (t + 2 < NKT) stage_half(Wg, col0, t + 2, Bs + (t & 1) * TE, 0, w, lane); }
      else             { if (t + 2 < NKT) stage_half(Wg, col0, t + 2, Bs + (t & 1) * TE, 1, w, lane); }
      asm volatile("" ::: "memory");
      __builtin_amdgcn_s_barrier();
      asm volatile("" ::: "memory");
      // --- MFMA cluster (16) ---
      __builtin_amdgcn_s_setprio(1);
#pragma unroll
      for (int f = 0; f < 2; ++f)
#pragma unroll
        for (int nf = 0; nf < 4; ++nf) {
          const int mf = q * 2 + f;
          acc[mf][nf] = __builtin_amdgcn_mfma_f32_16x16x32_bf16(af_[f][0], bf_[0][nf], acc[mf][nf], 0, 0, 0);
          acc[mf][nf] = __builtin_amdgcn_mfma_f32_16x16x32_bf16(af_[f][1], bf_[1][nf], acc[mf][nf], 0, 0, 0);
        }
      __builtin_amdgcn_s_setprio(0);
      asm volatile("" ::: "memory");
      // --- boundary wait: once per K-tile, counted, never 0 in steady state ---
      if (q == 3) {
        if (t < NKT - 2)       asm volatile("s_waitcnt vmcnt(4)" ::: "memory");
        else if (t == NKT - 2) asm volatile("s_waitcnt vmcnt(0)" ::: "memory");
      }
      __builtin_amdgcn_s_barrier();
      asm volatile("" ::: "memory");
    }
  }
}

// ---------------------------------------------------------------------------
// Kernel 3: QKV GEMM (256² 8-phase). Epilogue scatters q,k->[bh][n][64],
// v->[bh][64][n]. N-tiles of 256 lie entirely in one of q/k/v (768=3*256).
// ---------------------------------------------------------------------------
__global__ void __launch_bounds__(512, 2) gemm_qkv(const unsigned short* __restrict__ A,
                                                   const unsigned short* __restrict__ W,
                                                   unsigned short* __restrict__ qb,
                                                   unsigned short* __restrict__ kb,
                                                   unsigned short* __restrict__ vb) {
  __shared__ __align__(16) unsigned short As[2 * TE];
  __shared__ __align__(16) unsigned short Bs[2 * TE];
  const int tid = threadIdx.x, lane = tid & 63, w = tid >> 6;
  const int wr = w >> 2, wc = w & 3;
  const int lr = lane & 15, kg = lane >> 4;
  // XCD-aware swizzle: grid 1440 = 8 * 180
  const int bid = blockIdx.x;
  const int wg = (bid & 7) * 180 + (bid >> 3);
  const int bm = wg / 9, bn = wg % 9;
  const int row0 = bm * 256, col0 = bn * 256;

  f32x4 acc[8][4] = {};
  gemm_kloop(A, W, row0, col0, As, Bs, acc);

  const int which = bn / 3;                // 0=q 1=k 2=v (uniform per block)
  const int colq  = (bn % 3) * 256 + wc * 64;
  if (which == 2) {
#pragma unroll
    for (int mf = 0; mf < 8; ++mf) {
      const int m0 = row0 + wr * 128 + mf * 16 + kg * 4;
      const unsigned bq = (unsigned)m0 / 320u;
      const unsigned t0 = (unsigned)m0 - bq * 320u;
#pragma unroll
      for (int nf = 0; nf < 4; ++nf) {
        const int nn = colq + nf * 16 + lr;
        const int h = nn >> 6, dd = nn & 63;
        ushort4 o;
        o.x = f2bf(acc[mf][nf][0]); o.y = f2bf(acc[mf][nf][1]);
        o.z = f2bf(acc[mf][nf][2]); o.w = f2bf(acc[mf][nf][3]);
        *(ushort4*)&vb[(((int)bq * 12 + h) * 64 + dd) * 320 + (int)t0] = o;
      }
    }
  } else {
    unsigned short* dst = (which == 0) ? qb : kb;
#pragma unroll
    for (int mf = 0; mf < 8; ++mf) {
      const int m0 = row0 + wr * 128 + mf * 16 + kg * 4;
      const unsigned bq = (unsigned)m0 / 320u;
      const unsigned t0 = (unsigned)m0 - bq * 320u;
#pragma unroll
      for (int nf = 0; nf < 4; ++nf) {
        const int nn = colq + nf * 16 + lr;
        const int h = nn >> 6, dd = nn & 63;
        const int base = (((int)bq * 12 + h) * 320 + (int)t0) * 64 + dd;
#pragma unroll
        for (int r = 0; r < 4; r++)
          dst[base + r * 64] = f2bf(acc[mf][nf][r]);
      }
    }
  }
}

// ---------------------------------------------------------------------------
// Kernel 4: flash attention (unchanged from R1 — passed, ~95 µs est.)
// ---------------------------------------------------------------------------
__global__ void __launch_bounds__(256) attn(const unsigned short* __restrict__ qb,
                                            const unsigned short* __restrict__ kb,
                                            const unsigned short* __restrict__ vb,
                                            unsigned short* __restrict__ ab) {
  __shared__ __align__(16) unsigned short Ks[64 * 64];
  __shared__ __align__(16) unsigned short Vt[64 * 64];
  __shared__ __align__(16) unsigned short Pl[4 * 16 * 64];
  const int bid = blockIdx.x;
  const int qt = bid % 5, bh = bid / 5;
  const int tid = threadIdx.x, lane = tid & 63, w = tid >> 6;
  const int lr = lane & 15, kg = lane >> 4;

  const int qrow = qt * 64 + w * 16 + lr;
  const unsigned short* qptr = qb + (bh * 320 + qrow) * 64;
  const bf16x8 qa0 = *(const bf16x8*)(qptr + kg * 8);
  const bf16x8 qa1 = *(const bf16x8*)(qptr + 32 + kg * 8);

  f32x4 o[4] = {};
  float mrun[4] = {-1e30f, -1e30f, -1e30f, -1e30f};
  float lrun[4] = {0.f, 0.f, 0.f, 0.f};
  const int nchunk = (qt == 0) ? 1 : 5;

  const int c0 = w, c1 = w + 4;
  const int srow0 = c0 * 8 + (lane >> 3);
  const int srow1 = c1 * 8 + (lane >> 3);
  const int slot  = lane & 7;
  const int part0 = slot ^ (srow0 & 7);
  const int part1 = slot ^ (srow1 & 7);
  const unsigned short* kbase = kb + bh * 320 * 64;
  const unsigned short* vbase = vb + bh * 64 * 320;
  unsigned short* lk0 = &Ks[c0 * 512];
  unsigned short* lk1 = &Ks[c1 * 512];
  unsigned short* lv0 = &Vt[c0 * 512];
  unsigned short* lv1 = &Vt[c1 * 512];
  char* PwB = (char*)&Pl[w * 1024];

  for (int kc = 0; kc < nchunk; kc++) {
    gload16(kbase + (kc * 64 + srow0) * 64 + part0 * 8, lk0);
    gload16(kbase + (kc * 64 + srow1) * 64 + part1 * 8, lk1);
    gload16(vbase + srow0 * 320 + kc * 64 + part0 * 8, lv0);
    gload16(vbase + srow1 * 320 + kc * 64 + part1 * 8, lv1);
    __syncthreads();

    f32x4 s[4];
#pragma unroll
    for (int kt = 0; kt < 4; kt++) {
      const int key = kt * 16 + lr;
      const char* kr = (const char*)Ks + key * 128;
      const unsigned sw = (unsigned)((key & 7) << 4);
      bf16x8 k0 = *(const bf16x8*)(kr + ((kg * 16) ^ sw));
      bf16x8 k1 = *(const bf16x8*)(kr + ((64 + kg * 16) ^ sw));
      f32x4 z = {0.f, 0.f, 0.f, 0.f};
      z = __builtin_amdgcn_mfma_f32_16x16x32_bf16(qa0, k0, z, 0, 0, 0);
      z = __builtin_amdgcn_mfma_f32_16x16x32_bf16(qa1, k1, z, 0, 0, 0);
      s[kt] = z;
    }

#pragma unroll
    for (int r = 0; r < 4; r++) {
      float rm = fmaxf(fmaxf(s[0][r], s[1][r]), fmaxf(s[2][r], s[3][r]));
      rm = fmaxf(rm, __shfl_xor(rm, 1));
      rm = fmaxf(rm, __shfl_xor(rm, 2));
      rm = fmaxf(rm, __shfl_xor(rm, 4));
      rm = fmaxf(rm, __shfl_xor(rm, 8));
      const float mn = fmaxf(mrun[r], rm);
      const float alpha = __expf(mrun[r] - mn);
      mrun[r] = mn;
      const int q = kg * 4 + r;
      char* prow = PwB + q * 128;
      const unsigned sw = (unsigned)((q & 7) << 4);
      float rs = 0.f;
#pragma unroll
      for (int kt = 0; kt < 4; kt++) {
        const float p = __expf(s[kt][r] - mn);
        rs += p;
        const int key = kt * 16 + lr;
        *(unsigned short*)(prow + ((key * 2) ^ sw)) = f2bf(p);
      }
      rs += __shfl_xor(rs, 1);
      rs += __shfl_xor(rs, 2);
      rs += __shfl_xor(rs, 4);
      rs += __shfl_xor(rs, 8);
      lrun[r] = lrun[r] * alpha + rs;
#pragma unroll
      for (int dt = 0; dt < 4; dt++) o[dt][r] *= alpha;
    }

    asm volatile("s_waitcnt lgkmcnt(0)" ::: "memory");

    {
      const char* par = (const char*)PwB + lr * 128;
      const unsigned swp = (unsigned)((lr & 7) << 4);
      bf16x8 p0 = *(const bf16x8*)(par + ((kg * 16) ^ swp));
      bf16x8 p1 = *(const bf16x8*)(par + ((64 + kg * 16) ^ swp));
#pragma unroll
      for (int dt = 0; dt < 4; dt++) {
        const int d = dt * 16 + lr;
        const char* vr = (const char*)Vt + d * 128;
        const unsigned swv = (unsigned)((d & 7) << 4);
        bf16x8 v0 = *(const bf16x8*)(vr + ((kg * 16) ^ swv));
        bf16x8 v1 = *(const bf16x8*)(vr + ((64 + kg * 16) ^ swv));
        o[dt] = __builtin_amdgcn_mfma_f32_16x16x32_bf16(p0, v0, o[dt], 0, 0, 0);
        o[dt] = __builtin_amdgcn_mfma_f32_16x16x32_bf16(p1, v1, o[dt], 0, 0, 0);
      }
    }
    __syncthreads();
  }

  const int b = bh / 12, h = bh - b * 12;
#pragma unroll
  for (int r = 0; r < 4; r++) {
    const float inv = 1.0f / lrun[r];
    const int token = b * 320 + qt * 64 + w * 16 + kg * 4 + r;
    unsigned short* orow = ab + token * 768 + h * 64;
#pragma unroll
    for (int dt = 0; dt < 4; dt++)
      orow[dt * 16 + lr] = f2bf(o[dt][r] * inv);
  }
}

// ---------------------------------------------------------------------------
// Kernel 5: proj GEMM + bias (256² 8-phase), fp32 out.
// ---------------------------------------------------------------------------
__global__ void __launch_bounds__(512, 2) gemm_proj(const unsigned short* __restrict__ A,
                                                    const unsigned short* __restrict__ W,
                                                    const float* __restrict__ bias,
                                                    float* __restrict__ out) {
  __shared__ __align__(16) unsigned short As[2 * TE];
  __shared__ __align__(16) unsigned short Bs[2 * TE];
  const int tid = threadIdx.x, lane = tid & 63, w = tid >> 6;
  const int wr = w >> 2, wc = w & 3;
  const int lr = lane & 15, kg = lane >> 4;
  // XCD-aware swizzle: grid 480 = 8 * 60
  const int bid = blockIdx.x;
  const int wg = (bid & 7) * 60 + (bid >> 3);
  const int bm = wg / 3, bn = wg % 3;
  const int row0 = bm * 256, col0 = bn * 256;

  f32x4 acc[8][4] = {};
  gemm_kloop(A, W, row0, col0, As, Bs, acc);

#pragma unroll
  for (int nf = 0; nf < 4; ++nf) {
    const int nn = col0 + wc * 64 + nf * 16 + lr;
    const float bv = bias[nn];
#pragma unroll
    for (int mf = 0; mf < 8; ++mf) {
      const int m0 = row0 + wr * 128 + mf * 16 + kg * 4;
      float* po = out + (size_t)m0 * 768 + nn;
#pragma unroll
      for (int r = 0; r < 4; r++)
        po[(size_t)r * 768] = acc[mf][nf][r] + bv;
    }
  }
}

// ---------------------------------------------------------------------------
extern "C" void kernel_launch(void* const* d_in, const int* in_sizes, int n_in,
                              void* d_out, int out_size, void* d_ws, size_t ws_size,
                              hipStream_t stream) {
  (void)in_sizes; (void)n_in; (void)out_size; (void)ws_size;
  const float* x1     = (const float*)d_in[0];
  const float* x2     = (const float*)d_in[1];
  const float* qkv_w  = (const float*)d_in[2];
  const float* proj_w = (const float*)d_in[3];
  const float* proj_b = (const float*)d_in[4];
  float* out = (float*)d_out;

  const size_t TOK = (size_t)NT_ * C_;
  unsigned short* xb = (unsigned short*)d_ws;
  unsigned short* qb = xb + TOK;
  unsigned short* kb = qb + TOK;
  unsigned short* vb = kb + TOK;
  unsigned short* ab = vb + TOK;
  unsigned short* wq = ab + TOK;
  unsigned short* wp = wq + (size_t)K3_ * C_;

  prep_x<<<8192, 256, 0, stream>>>(x1, x2, xb);
  prep_w<<<2304, 256, 0, stream>>>(qkv_w, proj_w, wq, wp);
  gemm_qkv<<<160 * 9, 512, 0, stream>>>(xb, wq, qb, kb, vb);
  attn<<<1536 * 5, 256, 0, stream>>>(qb, kb, vb, ab);
  gemm_proj<<<160 * 3, 512, 0, stream>>>(ab, wp, proj_b, out);
}